// Round 2
// baseline (784.970 us; speedup 1.0000x reference)
//
#include <hip/hip_runtime.h>

#define NBATCH 8
#define NTOK   12
#define NN     207
#define DHID   256
#define LL     2484      // NTOK*NN
#define RR     6         // rows per block in k_attn (divides 2484)
#define NJ     10        // ceil(2484/256)
#define LNEPS  1e-5f

__device__ __forceinline__ float lane_bcast(float v, int l) {
    return __uint_as_float((unsigned)__builtin_amdgcn_readlane((int)__float_as_uint(v), l));
}

// ---------------- Kernel 1: LayerNorm + Q/K projections ----------------
__global__ __launch_bounds__(256) void k_lnproj(
    const float* __restrict__ x, const float* __restrict__ Wq, const float* __restrict__ bq,
    const float* __restrict__ Wk, const float* __restrict__ bk,
    const float* __restrict__ gamma, const float* __restrict__ beta,
    float* __restrict__ Xn, float* __restrict__ Qb, float* __restrict__ Kb)
{
    __shared__ float xrow[4][64];
    int w = threadIdx.x >> 6, lane = threadIdx.x & 63;
    size_t row = (size_t)blockIdx.x * 4 + w;
    float xv = x[row * 64 + lane];
    float m = xv;
    #pragma unroll
    for (int o = 32; o; o >>= 1) m += __shfl_xor(m, o, 64);
    m *= (1.0f / 64.0f);
    float dv = xv - m;
    float var = dv * dv;
    #pragma unroll
    for (int o = 32; o; o >>= 1) var += __shfl_xor(var, o, 64);
    var *= (1.0f / 64.0f);
    float xg = dv * (1.0f / sqrtf(var + LNEPS)) * gamma[lane] + beta[lane];
    Xn[row * 64 + lane] = xg;
    xrow[w][lane] = xg;
    __syncthreads();
    float q = bq[lane], k = bk[lane];
    #pragma unroll 8
    for (int e = 0; e < 64; e++) {
        float xe = xrow[w][e];
        q += xe * Wq[e * 64 + lane];
        k += xe * Wk[e * 64 + lane];
    }
    Qb[row * 64 + lane] = q;
    Kb[row * 64 + lane] = k;
}

// --------------- radix-select helper: one 8-bit step for one row ---------------
__device__ __forceinline__ void radix_step(const unsigned* histu, int r, int lane,
                                           unsigned& kr, unsigned& pfx, unsigned* prefix_lds)
{
    unsigned c0 = histu[r * 256 + lane * 4 + 0];
    unsigned c1 = histu[r * 256 + lane * 4 + 1];
    unsigned c2 = histu[r * 256 + lane * 4 + 2];
    unsigned c3 = histu[r * 256 + lane * 4 + 3];
    unsigned S = c0 + c1 + c2 + c3;
    unsigned T = S;
    #pragma unroll
    for (int off = 1; off < 64; off <<= 1) {
        unsigned t = __shfl_down(T, off, 64);
        T += (lane + off < 64) ? t : 0u;
    }
    unsigned Tn = T - S;                       // suffix sum starting at lane+1
    unsigned sfx3 = c3 + Tn, sfx2 = c2 + sfx3, sfx1 = c1 + sfx2, sfx0 = c0 + sfx1;
    int hit = -1; unsigned nk = 0u;
    if (sfx3 >= kr && Tn   < kr) { hit = lane * 4 + 3; nk = kr - Tn; }
    if (sfx2 >= kr && sfx3 < kr) { hit = lane * 4 + 2; nk = kr - sfx3; }
    if (sfx1 >= kr && sfx2 < kr) { hit = lane * 4 + 1; nk = kr - sfx2; }
    if (sfx0 >= kr && sfx1 < kr) { hit = lane * 4 + 0; nk = kr - sfx1; }
    unsigned long long mask = __ballot(hit >= 0);
    int src = __ffsll((unsigned long long)mask) - 1;
    int bin = __shfl(hit, src, 64);
    nk = (unsigned)__shfl((int)nk, src, 64);
    pfx = (pfx << 8) | (unsigned)bin;
    kr = nk;
    if (lane == 0) prefix_lds[r] = pfx;
}

// ---------------- Kernel 2: fused scores + top-k + softmax + PV (s in registers) ----------------
__global__ __launch_bounds__(256, 3) void k_attn(
    const float* __restrict__ Xn, const float* __restrict__ Qb, const float* __restrict__ Kb,
    const float* __restrict__ stg, const int* __restrict__ topk_p,
    float* __restrict__ Z)
{
    __shared__ float q_lds[RR][64];
    __shared__ unsigned histu[RR * 256];
    __shared__ unsigned prefix_lds[RR];
    __shared__ float redmax[4][RR];
    __shared__ float redsum[4][RR];
    __shared__ float red_pv[4][RR][64];

    int tid = threadIdx.x;
    int lane = tid & 63, wv = tid >> 6;
    int b = blockIdx.x & 7;
    int chunk = blockIdx.x >> 3;
    int row0 = chunk * RR;
    const float* Kbase = Kb + (size_t)b * LL * 64;
    const float* Xbase = Xn + (size_t)b * LL * 64;

    for (int i = tid; i < RR * 64; i += 256)
        q_lds[i >> 6][i & 63] = Qb[((size_t)b * LL + row0 + (i >> 6)) * 64 + (i & 63)];
    int keff;
    { int tk = *topk_p; keff = (tk < 5) ? tk * NN : tk; }
    __syncthreads();

    // ---- A: scores dg = q . k, all in registers ----
    float sreg[RR * NJ];
    #pragma unroll
    for (int i = 0; i < RR * NJ; i++) sreg[i] = 0.f;
    for (int dc = 0; dc < 64; dc += 4) {
        float4 qc[RR];
        #pragma unroll
        for (int r = 0; r < RR; r++) qc[r] = *(const float4*)&q_lds[r][dc];
        #pragma unroll
        for (int sl = 0; sl < NJ; sl++) {
            int j = tid + sl * 256;
            if (j < LL) {
                float4 kv = *(const float4*)(Kbase + (size_t)j * 64 + dc);
                #pragma unroll
                for (int r = 0; r < RR; r++)
                    sreg[r * NJ + sl] += qc[r].x * kv.x + qc[r].y * kv.y
                                       + qc[r].z * kv.z + qc[r].w * kv.w;
            }
        }
    }

    // ---- B: s = sigmoid(dg/8) * stg (in regs), per-thread max ----
    float mxr[RR];
    #pragma unroll
    for (int r = 0; r < RR; r++) mxr[r] = 0.f;
    const float* stgp = stg + ((size_t)b * LL + row0) * LL;
    #pragma unroll
    for (int sl = 0; sl < NJ; sl++) {
        int j = tid + sl * 256;
        if (j < LL) {
            #pragma unroll
            for (int r = 0; r < RR; r++) {
                float sg = 1.0f / (1.0f + __expf(sreg[r * NJ + sl] * -0.125f));
                float sv = sg * stgp[(size_t)r * LL + j];
                sreg[r * NJ + sl] = sv;
                mxr[r] = fmaxf(mxr[r], sv);
            }
        }
    }

    // ---- C: block max ----
    #pragma unroll
    for (int r = 0; r < RR; r++) {
        float v = mxr[r];
        #pragma unroll
        for (int o = 32; o; o >>= 1) v = fmaxf(v, __shfl_xor(v, o, 64));
        mxr[r] = v;
    }
    if (lane == 0) {
        #pragma unroll
        for (int r = 0; r < RR; r++) redmax[wv][r] = mxr[r];
    }

    // ---- D: exact top-24-bit radix select from registers (3 passes) ----
    unsigned krA = (unsigned)keff, pfxA = 0u, krB = (unsigned)keff, pfxB = 0u;
    for (int pass = 0; pass < 3; pass++) {
        #pragma unroll
        for (int i = 0; i < RR; i++) histu[i * 256 + tid] = 0u;
        __syncthreads();
        unsigned pf[RR];
        #pragma unroll
        for (int r = 0; r < RR; r++) pf[r] = prefix_lds[r];   // unused on pass 0
        int shift = 24 - pass * 8;
        #pragma unroll
        for (int sl = 0; sl < NJ; sl++) {
            int j = tid + sl * 256;
            if (j < LL) {
                #pragma unroll
                for (int r = 0; r < RR; r++) {
                    unsigned vb = __float_as_uint(sreg[r * NJ + sl]);
                    bool match = (pass == 0) || ((vb >> (shift + 8)) == pf[r]);
                    if (match) atomicAdd(&histu[r * 256 + ((vb >> shift) & 255u)], 1u);
                }
            }
        }
        __syncthreads();
        radix_step(histu, wv, lane, krA, pfxA, prefix_lds);       // rows 0..3
        if (wv < 2) radix_step(histu, wv + 4, lane, krB, pfxB, prefix_lds); // rows 4,5
        __syncthreads();
    }

    // ---- E: e = (s > thr) ? exp(s - max) : 0, in regs; row sums ----
    float thrv[RR], mxv[RR], smr[RR];
    #pragma unroll
    for (int r = 0; r < RR; r++) {
        thrv[r] = __uint_as_float(prefix_lds[r] << 8);
        mxv[r] = fmaxf(fmaxf(redmax[0][r], redmax[1][r]), fmaxf(redmax[2][r], redmax[3][r]));
        smr[r] = 0.f;
    }
    #pragma unroll
    for (int sl = 0; sl < NJ; sl++) {
        #pragma unroll
        for (int r = 0; r < RR; r++) {
            float sv = sreg[r * NJ + sl];
            float e = (sv > thrv[r]) ? __expf(sv - mxv[r]) : 0.f;
            sreg[r * NJ + sl] = e;
            smr[r] += e;
        }
    }
    #pragma unroll
    for (int r = 0; r < RR; r++) {
        float v = smr[r];
        #pragma unroll
        for (int o = 32; o; o >>= 1) v += __shfl_xor(v, o, 64);
        smr[r] = v;
    }
    if (lane == 0) {
        #pragma unroll
        for (int r = 0; r < RR; r++) redsum[wv][r] = smr[r];
    }
    __syncthreads();

    // ---- F: o = e @ Xn via readlane broadcast from registers ----
    float acc[RR];
    #pragma unroll
    for (int r = 0; r < RR; r++) acc[r] = 0.f;
    #pragma unroll
    for (int sl = 0; sl < NJ; sl++) {
        int jbase = sl * 256 + wv * 64;
        int lim = LL - jbase;
        const float* xp = Xbase + (size_t)jbase * 64 + lane;
        if (lim >= 64) {
            #pragma unroll 4
            for (int l2 = 0; l2 < 64; l2++) {
                float xv = xp[(size_t)l2 * 64];
                #pragma unroll
                for (int r = 0; r < RR; r++)
                    acc[r] = fmaf(lane_bcast(sreg[r * NJ + sl], l2), xv, acc[r]);
            }
        } else if (lim > 0) {
            for (int l2 = 0; l2 < lim; l2++) {
                float xv = xp[(size_t)l2 * 64];
                #pragma unroll
                for (int r = 0; r < RR; r++)
                    acc[r] = fmaf(lane_bcast(sreg[r * NJ + sl], l2), xv, acc[r]);
            }
        }
    }
    #pragma unroll
    for (int r = 0; r < RR; r++) red_pv[wv][r][lane] = acc[r];
    __syncthreads();
    for (int i = tid; i < RR * 64; i += 256) {
        int r = i >> 6, d = i & 63;
        float rcp = 1.0f / (redsum[0][r] + redsum[1][r] + redsum[2][r] + redsum[3][r]);
        float o = (red_pv[0][r][d] + red_pv[1][r][d]) + (red_pv[2][r][d] + red_pv[3][r][d]);
        size_t grow = (size_t)b * LL + row0 + r;
        Z[grow * 64 + d] = o * rcp + Xbase[(size_t)(row0 + r) * 64 + d];
    }
}

// ---------------- Kernel 3: fused LN + FFN + residual ----------------
__global__ __launch_bounds__(256) void k_ffn(
    const float* __restrict__ Zb, const float* __restrict__ fg, const float* __restrict__ fb,
    const float* __restrict__ w1, const float* __restrict__ b1,
    const float* __restrict__ w2, const float* __restrict__ b2,
    float* __restrict__ out)
{
    const int G = 16;
    __shared__ float zr[G][64];
    __shared__ float zl[G][64];
    __shared__ float h[G][DHID];
    int tid = threadIdx.x;
    int w = tid >> 6, lane = tid & 63;
    size_t row0 = (size_t)blockIdx.x * G;
    for (int rr = w; rr < G; rr += 4) {
        float zv = Zb[(row0 + rr) * 64 + lane];
        zr[rr][lane] = zv;
        float m = zv;
        #pragma unroll
        for (int o = 32; o; o >>= 1) m += __shfl_xor(m, o, 64);
        m *= (1.0f / 64.0f);
        float dv = zv - m;
        float var = dv * dv;
        #pragma unroll
        for (int o = 32; o; o >>= 1) var += __shfl_xor(var, o, 64);
        var *= (1.0f / 64.0f);
        zl[rr][lane] = dv * (1.0f / sqrtf(var + LNEPS)) * fg[lane] + fb[lane];
    }
    __syncthreads();
    float hacc[G];
    #pragma unroll
    for (int g = 0; g < G; g++) hacc[g] = 0.f;
    for (int d = 0; d < 64; d++) {
        float wv1 = w1[d * DHID + tid];
        #pragma unroll
        for (int g = 0; g < G; g++) hacc[g] += zl[g][d] * wv1;
    }
    float b1v = b1[tid];
    #pragma unroll
    for (int g = 0; g < G; g++) h[g][tid] = fmaxf(hacc[g] + b1v, 0.f);
    __syncthreads();
    float oacc[4] = {0.f, 0.f, 0.f, 0.f};
    for (int i = 0; i < DHID; i++) {
        float wv2 = w2[i * 64 + lane];
        #pragma unroll
        for (int rr = 0; rr < 4; rr++) oacc[rr] += h[w * 4 + rr][i] * wv2;
    }
    float b2v = b2[lane];
    #pragma unroll
    for (int rr = 0; rr < 4; rr++)
        out[(row0 + w * 4 + rr) * 64 + lane] = zr[w * 4 + rr][lane] + oacc[rr] + b2v;
}

extern "C" void kernel_launch(void* const* d_in, const int* in_sizes, int n_in,
                              void* d_out, int out_size, void* d_ws, size_t ws_size,
                              hipStream_t stream)
{
    const float* x      = (const float*)d_in[0];
    const float* stg    = (const float*)d_in[1];
    const float* Wq     = (const float*)d_in[2];
    const float* bq     = (const float*)d_in[3];
    const float* Wk     = (const float*)d_in[4];
    const float* bk     = (const float*)d_in[5];
    const float* gamma  = (const float*)d_in[6];
    const float* beta   = (const float*)d_in[7];
    const float* fgamma = (const float*)d_in[8];
    const float* fbeta  = (const float*)d_in[9];
    const float* w1     = (const float*)d_in[10];
    const float* b1     = (const float*)d_in[11];
    const float* w2     = (const float*)d_in[12];
    const float* b2     = (const float*)d_in[13];
    const int*   topk   = (const int*)d_in[14];
    float* out = (float*)d_out;

    const size_t rows = (size_t)NBATCH * NTOK * NN;   // 19872
    float* Xn = (float*)d_ws;
    float* Qb = Xn + rows * 64;
    float* Kb = Qb + rows * 64;
    float* Z  = Kb + rows * 64;

    k_lnproj<<<(int)(rows / 4), 256, 0, stream>>>(x, Wq, bq, Wk, bk, gamma, beta, Xn, Qb, Kb);
    k_attn<<<NBATCH * (LL / RR), 256, 0, stream>>>(Xn, Qb, Kb, stg, topk, Z);
    k_ffn<<<(int)(rows / 16), 256, 0, stream>>>(Z, fgamma, fbeta, w1, b1, w2, b2, out);
}

// Round 3
// 609.511 us; speedup vs baseline: 1.2879x; 1.2879x over previous
//
#include <hip/hip_runtime.h>

#define NBATCH 8
#define NTOK   12
#define NN     207
#define DHID   256
#define LL     2484      // NTOK*NN
#define RR     6         // rows per block in k_attn (divides 2484)
#define NJ     10        // ceil(2484/256)
#define LNEPS  1e-5f

__device__ __forceinline__ float lane_bcast(float v, int l) {
    return __uint_as_float((unsigned)__builtin_amdgcn_readlane((int)__float_as_uint(v), l));
}

// ---------------- Kernel 1: LayerNorm + Q/K projections ----------------
__global__ __launch_bounds__(256) void k_lnproj(
    const float* __restrict__ x, const float* __restrict__ Wq, const float* __restrict__ bq,
    const float* __restrict__ Wk, const float* __restrict__ bk,
    const float* __restrict__ gamma, const float* __restrict__ beta,
    float* __restrict__ Xn, float* __restrict__ Qb, float* __restrict__ Kb)
{
    __shared__ float xrow[4][64];
    int w = threadIdx.x >> 6, lane = threadIdx.x & 63;
    size_t row = (size_t)blockIdx.x * 4 + w;
    float xv = x[row * 64 + lane];
    float m = xv;
    #pragma unroll
    for (int o = 32; o; o >>= 1) m += __shfl_xor(m, o, 64);
    m *= (1.0f / 64.0f);
    float dv = xv - m;
    float var = dv * dv;
    #pragma unroll
    for (int o = 32; o; o >>= 1) var += __shfl_xor(var, o, 64);
    var *= (1.0f / 64.0f);
    float xg = dv * (1.0f / sqrtf(var + LNEPS)) * gamma[lane] + beta[lane];
    Xn[row * 64 + lane] = xg;
    xrow[w][lane] = xg;
    __syncthreads();
    float q = bq[lane], k = bk[lane];
    #pragma unroll 8
    for (int e = 0; e < 64; e++) {
        float xe = xrow[w][e];
        q += xe * Wq[e * 64 + lane];
        k += xe * Wk[e * 64 + lane];
    }
    Qb[row * 64 + lane] = q;
    Kb[row * 64 + lane] = k;
}

// --------------- suffix-scan select: find bin where cumulative-from-top crosses kr ---------------
// h: 256 counts for this row. Updates kr to remaining count inside chosen bin; returns bin.
__device__ __forceinline__ int scan_select(const unsigned* __restrict__ h, int lane, unsigned& kr)
{
    unsigned c0 = h[lane * 4 + 0];
    unsigned c1 = h[lane * 4 + 1];
    unsigned c2 = h[lane * 4 + 2];
    unsigned c3 = h[lane * 4 + 3];
    unsigned S = c0 + c1 + c2 + c3;
    unsigned T = S;
    #pragma unroll
    for (int off = 1; off < 64; off <<= 1) {
        unsigned t = __shfl_down(T, off, 64);
        T += (lane + off < 64) ? t : 0u;
    }
    unsigned Tn = T - S;                       // suffix sum starting at lane*4+4
    unsigned sfx3 = c3 + Tn, sfx2 = c2 + sfx3, sfx1 = c1 + sfx2, sfx0 = c0 + sfx1;
    int hit = -1; unsigned nk = 0u;
    if (sfx3 >= kr && Tn   < kr) { hit = lane * 4 + 3; nk = kr - Tn; }
    if (sfx2 >= kr && sfx3 < kr) { hit = lane * 4 + 2; nk = kr - sfx3; }
    if (sfx1 >= kr && sfx2 < kr) { hit = lane * 4 + 1; nk = kr - sfx2; }
    if (sfx0 >= kr && sfx1 < kr) { hit = lane * 4 + 0; nk = kr - sfx1; }
    unsigned long long mask = __ballot(hit >= 0);
    int src = __ffsll((unsigned long long)mask) - 1;
    int bin = __shfl(hit, src, 64);
    kr = (unsigned)__shfl((int)nk, src, 64);
    return bin;
}

// ---------------- Kernel 2: fused scores + top-k + softmax + PV ----------------
__global__ __launch_bounds__(256, 3) void k_attn(
    const float* __restrict__ Xn, const float* __restrict__ Qb, const float* __restrict__ Kb,
    const float* __restrict__ stg, const int* __restrict__ topk_p,
    float* __restrict__ Z)
{
    __shared__ unsigned h1[RR * 256];          // pass-0 value-domain histograms (6 KB)
    __shared__ unsigned h2[RR * 256];          // pass-1 refine histograms (6 KB)
    __shared__ int   b0_lds[RR];
    __shared__ float thr_lds[RR];
    __shared__ float redmax[4][RR];
    __shared__ float redsum[4][RR];
    __shared__ float red_pv[4][RR][64];

    int tid = threadIdx.x;
    int lane = tid & 63, wv = tid >> 6;
    int b = blockIdx.x & 7;
    int chunk = blockIdx.x >> 3;
    int row0 = chunk * RR;
    const float* Kbase = Kb + (size_t)b * LL * 64;
    const float* Xbase = Xn + (size_t)b * LL * 64;
    const float* qrow  = Qb + ((size_t)b * LL + row0) * 64;   // wave-uniform reads -> SGPR

    int keff;
    { int tk = *topk_p; keff = (tk < 5) ? tk * NN : tk; }

    // zero both histograms up front (one barrier)
    #pragma unroll
    for (int i = 0; i < RR; i++) { h1[i * 256 + tid] = 0u; h2[i * 256 + tid] = 0u; }
    __syncthreads();

    // ---- A: scores dg = q . k ; q chunks in SGPRs, K streamed L1-resident ----
    float sreg[RR * NJ];
    #pragma unroll
    for (int i = 0; i < RR * NJ; i++) sreg[i] = 0.f;
    #pragma unroll
    for (int half = 0; half < 2; half++) {
        #pragma unroll 1
        for (int dcg = 0; dcg < 8; dcg++) {
            float qc[RR][8];
            #pragma unroll
            for (int r = 0; r < RR; r++)
                #pragma unroll
                for (int u = 0; u < 8; u++) qc[r][u] = qrow[r * 64 + dcg * 8 + u];
            #pragma unroll
            for (int sl5 = 0; sl5 < 5; sl5++) {
                int sl = half * 5 + sl5;
                int j = tid + sl * 256;
                if (j < LL) {
                    const float4* kp = (const float4*)(Kbase + (size_t)j * 64 + dcg * 8);
                    float4 k0 = kp[0], k1 = kp[1];
                    #pragma unroll
                    for (int r = 0; r < RR; r++) {
                        float a = qc[r][0] * k0.x + qc[r][1] * k0.y
                                + qc[r][2] * k0.z + qc[r][3] * k0.w;
                        float c = qc[r][4] * k1.x + qc[r][5] * k1.y
                                + qc[r][6] * k1.z + qc[r][7] * k1.w;
                        sreg[r * NJ + half * 5 + sl5] += a + c;
                    }
                }
            }
        }
    }

    // ---- B: s = sigmoid(dg/8)*stg (regs); fold per-thread max + pass-0 histogram ----
    float mxr[RR];
    #pragma unroll
    for (int r = 0; r < RR; r++) mxr[r] = 0.f;
    const float* stgp = stg + ((size_t)b * LL + row0) * LL;
    #pragma unroll
    for (int sl = 0; sl < NJ; sl++) {
        int j = tid + sl * 256;
        if (j < LL) {
            #pragma unroll
            for (int r = 0; r < RR; r++) {
                float sg = 1.0f / (1.0f + __expf(sreg[r * NJ + sl] * -0.125f));
                float sv = sg * stgp[(size_t)r * LL + j];
                sreg[r * NJ + sl] = sv;
                mxr[r] = fmaxf(mxr[r], sv);
                int g = (int)(sv * 65536.0f); g = min(g, 65535);
                atomicAdd(&h1[r * 256 + (g >> 8)], 1u);
            }
        }
    }
    #pragma unroll
    for (int r = 0; r < RR; r++) {
        float v = mxr[r];
        #pragma unroll
        for (int o = 32; o; o >>= 1) v = fmaxf(v, __shfl_xor(v, o, 64));
        mxr[r] = v;
    }
    if (lane == 0) {
        #pragma unroll
        for (int r = 0; r < RR; r++) redmax[wv][r] = mxr[r];
    }
    __syncthreads();

    // ---- pass-0 scan: coarse bin per row ----
    unsigned krA = (unsigned)keff, krB = (unsigned)keff;
    {
        int binA = scan_select(&h1[wv * 256], lane, krA);
        if (lane == 0) b0_lds[wv] = binA;
        if (wv < 2) {
            int binB = scan_select(&h1[(wv + 4) * 256], lane, krB);
            if (lane == 0) b0_lds[wv + 4] = binB;
        }
    }
    __syncthreads();

    // ---- pass-1: refine within coarse bin ----
    {
        int b0c[RR];
        #pragma unroll
        for (int r = 0; r < RR; r++) b0c[r] = b0_lds[r];
        #pragma unroll
        for (int sl = 0; sl < NJ; sl++) {
            int j = tid + sl * 256;
            if (j < LL) {
                #pragma unroll
                for (int r = 0; r < RR; r++) {
                    int g = (int)(sreg[r * NJ + sl] * 65536.0f); g = min(g, 65535);
                    if ((g >> 8) == b0c[r]) atomicAdd(&h2[r * 256 + (g & 255)], 1u);
                }
            }
        }
    }
    __syncthreads();
    {
        int binA = scan_select(&h2[wv * 256], lane, krA);
        if (lane == 0) thr_lds[wv] = (float)(b0_lds[wv] * 256 + binA + 1) * (1.0f / 65536.0f);
        if (wv < 2) {
            int binB = scan_select(&h2[(wv + 4) * 256], lane, krB);
            if (lane == 0) thr_lds[wv + 4] = (float)(b0_lds[wv + 4] * 256 + binB + 1) * (1.0f / 65536.0f);
        }
    }
    __syncthreads();

    // ---- E: e = (s > thr) ? exp(s - max) : 0, in regs; row sums ----
    float thrv[RR], mxv[RR], smr[RR];
    #pragma unroll
    for (int r = 0; r < RR; r++) {
        thrv[r] = thr_lds[r];
        mxv[r] = fmaxf(fmaxf(redmax[0][r], redmax[1][r]), fmaxf(redmax[2][r], redmax[3][r]));
        smr[r] = 0.f;
    }
    #pragma unroll
    for (int sl = 0; sl < NJ; sl++) {
        #pragma unroll
        for (int r = 0; r < RR; r++) {
            float sv = sreg[r * NJ + sl];
            float e = (sv > thrv[r]) ? __expf(sv - mxv[r]) : 0.f;
            sreg[r * NJ + sl] = e;
            smr[r] += e;
        }
    }
    #pragma unroll
    for (int r = 0; r < RR; r++) {
        float v = smr[r];
        #pragma unroll
        for (int o = 32; o; o >>= 1) v += __shfl_xor(v, o, 64);
        smr[r] = v;
    }
    if (lane == 0) {
        #pragma unroll
        for (int r = 0; r < RR; r++) redsum[wv][r] = smr[r];
    }

    // ---- F: o = e @ Xn via readlane broadcast (8 loads in flight) ----
    float acc[RR];
    #pragma unroll
    for (int r = 0; r < RR; r++) acc[r] = 0.f;
    #pragma unroll
    for (int sl = 0; sl < NJ; sl++) {
        int jbase = sl * 256 + wv * 64;
        int lim = LL - jbase;
        const float* xp = Xbase + (size_t)jbase * 64 + lane;
        if (lim >= 64) {
            #pragma unroll 8
            for (int l2 = 0; l2 < 64; l2++) {
                float xv = xp[(size_t)l2 * 64];
                #pragma unroll
                for (int r = 0; r < RR; r++)
                    acc[r] = fmaf(lane_bcast(sreg[r * NJ + sl], l2), xv, acc[r]);
            }
        } else if (lim > 0) {
            for (int l2 = 0; l2 < lim; l2++) {
                float xv = xp[(size_t)l2 * 64];
                #pragma unroll
                for (int r = 0; r < RR; r++)
                    acc[r] = fmaf(lane_bcast(sreg[r * NJ + sl], l2), xv, acc[r]);
            }
        }
    }
    #pragma unroll
    for (int r = 0; r < RR; r++) red_pv[wv][r][lane] = acc[r];
    __syncthreads();
    for (int i = tid; i < RR * 64; i += 256) {
        int r = i >> 6, d = i & 63;
        float rcp = 1.0f / (redsum[0][r] + redsum[1][r] + redsum[2][r] + redsum[3][r]);
        float o = (red_pv[0][r][d] + red_pv[1][r][d]) + (red_pv[2][r][d] + red_pv[3][r][d]);
        size_t grow = (size_t)b * LL + row0 + r;
        Z[grow * 64 + d] = o * rcp + Xbase[(size_t)(row0 + r) * 64 + d];
    }
}

// ---------------- Kernel 3: fused LN + FFN + residual ----------------
__global__ __launch_bounds__(256) void k_ffn(
    const float* __restrict__ Zb, const float* __restrict__ fg, const float* __restrict__ fb,
    const float* __restrict__ w1, const float* __restrict__ b1,
    const float* __restrict__ w2, const float* __restrict__ b2,
    float* __restrict__ out)
{
    const int G = 16;
    __shared__ float zr[G][64];
    __shared__ float zl[G][64];
    __shared__ float h[G][DHID];
    int tid = threadIdx.x;
    int w = tid >> 6, lane = tid & 63;
    size_t row0 = (size_t)blockIdx.x * G;
    for (int rr = w; rr < G; rr += 4) {
        float zv = Zb[(row0 + rr) * 64 + lane];
        zr[rr][lane] = zv;
        float m = zv;
        #pragma unroll
        for (int o = 32; o; o >>= 1) m += __shfl_xor(m, o, 64);
        m *= (1.0f / 64.0f);
        float dv = zv - m;
        float var = dv * dv;
        #pragma unroll
        for (int o = 32; o; o >>= 1) var += __shfl_xor(var, o, 64);
        var *= (1.0f / 64.0f);
        zl[rr][lane] = dv * (1.0f / sqrtf(var + LNEPS)) * fg[lane] + fb[lane];
    }
    __syncthreads();
    float hacc[G];
    #pragma unroll
    for (int g = 0; g < G; g++) hacc[g] = 0.f;
    for (int d = 0; d < 64; d++) {
        float wv1 = w1[d * DHID + tid];
        #pragma unroll
        for (int g = 0; g < G; g++) hacc[g] += zl[g][d] * wv1;
    }
    float b1v = b1[tid];
    #pragma unroll
    for (int g = 0; g < G; g++) h[g][tid] = fmaxf(hacc[g] + b1v, 0.f);
    __syncthreads();
    float oacc[4] = {0.f, 0.f, 0.f, 0.f};
    for (int i = 0; i < DHID; i++) {
        float wv2 = w2[i * 64 + lane];
        #pragma unroll
        for (int rr = 0; rr < 4; rr++) oacc[rr] += h[w * 4 + rr][i] * wv2;
    }
    float b2v = b2[lane];
    #pragma unroll
    for (int rr = 0; rr < 4; rr++)
        out[(row0 + w * 4 + rr) * 64 + lane] = zr[w * 4 + rr][lane] + oacc[rr] + b2v;
}

extern "C" void kernel_launch(void* const* d_in, const int* in_sizes, int n_in,
                              void* d_out, int out_size, void* d_ws, size_t ws_size,
                              hipStream_t stream)
{
    const float* x      = (const float*)d_in[0];
    const float* stg    = (const float*)d_in[1];
    const float* Wq     = (const float*)d_in[2];
    const float* bq     = (const float*)d_in[3];
    const float* Wk     = (const float*)d_in[4];
    const float* bk     = (const float*)d_in[5];
    const float* gamma  = (const float*)d_in[6];
    const float* beta   = (const float*)d_in[7];
    const float* fgamma = (const float*)d_in[8];
    const float* fbeta  = (const float*)d_in[9];
    const float* w1     = (const float*)d_in[10];
    const float* b1     = (const float*)d_in[11];
    const float* w2     = (const float*)d_in[12];
    const float* b2     = (const float*)d_in[13];
    const int*   topk   = (const int*)d_in[14];
    float* out = (float*)d_out;

    const size_t rows = (size_t)NBATCH * NTOK * NN;   // 19872
    float* Xn = (float*)d_ws;
    float* Qb = Xn + rows * 64;
    float* Kb = Qb + rows * 64;
    float* Z  = Kb + rows * 64;

    k_lnproj<<<(int)(rows / 4), 256, 0, stream>>>(x, Wq, bq, Wk, bk, gamma, beta, Xn, Qb, Kb);
    k_attn<<<NBATCH * (LL / RR), 256, 0, stream>>>(Xn, Qb, Kb, stg, topk, Z);
    k_ffn<<<(int)(rows / 16), 256, 0, stream>>>(Z, fgamma, fbeta, w1, b1, w2, b2, out);
}

// Round 4
// 469.774 us; speedup vs baseline: 1.6710x; 1.2975x over previous
//
#include <hip/hip_runtime.h>

#define NBATCH 8
#define NTOK   12
#define NN     207
#define DHID   256
#define LL     2484      // NTOK*NN
#define LLP    2496      // padded to multiple of 32
#define RR     6         // rows per block in k_attn
#define ROWB   (LLP*2)   // bytes per row of s/e LDS buffer
#define LNEPS  1e-5f

typedef __attribute__((ext_vector_type(8)))  short bf16x8;
typedef __attribute__((ext_vector_type(16))) float f32x16;

__device__ __forceinline__ short f2bf(float f) {
    unsigned u = __float_as_uint(f);
    unsigned r = (u + 0x7FFFu + ((u >> 16) & 1u)) >> 16;
    return (short)r;
}
__device__ __forceinline__ unsigned sw_off(int r, unsigned byte) {
    return byte ^ ((unsigned)(r & 7) << 4);
}

// ---------------- Kernel 1: LayerNorm + Q/K projections ----------------
__global__ __launch_bounds__(256) void k_lnproj(
    const float* __restrict__ x, const float* __restrict__ Wq, const float* __restrict__ bq,
    const float* __restrict__ Wk, const float* __restrict__ bk,
    const float* __restrict__ gamma, const float* __restrict__ beta,
    float* __restrict__ Xn, float* __restrict__ Qb, short* __restrict__ Kbf)
{
    __shared__ float xrow[4][64];
    int w = threadIdx.x >> 6, lane = threadIdx.x & 63;
    size_t row = (size_t)blockIdx.x * 4 + w;
    float xv = x[row * 64 + lane];
    float m = xv;
    #pragma unroll
    for (int o = 32; o; o >>= 1) m += __shfl_xor(m, o, 64);
    m *= (1.0f / 64.0f);
    float dv = xv - m;
    float var = dv * dv;
    #pragma unroll
    for (int o = 32; o; o >>= 1) var += __shfl_xor(var, o, 64);
    var *= (1.0f / 64.0f);
    float xg = dv * (1.0f / sqrtf(var + LNEPS)) * gamma[lane] + beta[lane];
    Xn[row * 64 + lane] = xg;
    xrow[w][lane] = xg;
    __syncthreads();
    float q = bq[lane], k = bk[lane];
    #pragma unroll 8
    for (int e = 0; e < 64; e++) {
        float xe = xrow[w][e];
        q += xe * Wq[e * 64 + lane];
        k += xe * Wk[e * 64 + lane];
    }
    Qb[row * 64 + lane] = q;
    int br = (int)(row / LL);
    int jl = (int)(row - (size_t)br * LL);
    Kbf[((size_t)br * LLP + jl) * 64 + lane] = f2bf(k);
}

// ---------------- Kernel 1b: transpose Xn -> bf16 X^T, zero pads ----------------
__global__ __launch_bounds__(256) void k_prep(
    const float* __restrict__ Xn, short* __restrict__ XbfT, short* __restrict__ Kbf)
{
    __shared__ float tile[64][65];
    int bb = blockIdx.x & 7;
    int jt = blockIdx.x >> 3;          // 0..38
    int j0 = jt * 64;
    for (int i = threadIdx.x; i < 4096; i += 256) {
        int jl = i >> 6, d = i & 63;
        int j = j0 + jl;
        tile[jl][d] = (j < LL) ? Xn[((size_t)bb * LL + j) * 64 + d] : 0.f;
    }
    __syncthreads();
    for (int i = threadIdx.x; i < 4096; i += 256) {
        int d = i >> 6, jl = i & 63;
        XbfT[((size_t)bb * 64 + d) * LLP + j0 + jl] = f2bf(tile[jl][d]);
    }
    if (jt == 38) {
        for (int i = threadIdx.x; i < (LLP - LL) * 64; i += 256) {
            int jl = i >> 6, d = i & 63;
            Kbf[((size_t)bb * LLP + LL + jl) * 64 + d] = 0;
        }
    }
}

// --------------- suffix-scan select ---------------
__device__ __forceinline__ int scan_select(const unsigned* __restrict__ h, int lane, unsigned& kr)
{
    unsigned c0 = h[lane * 4 + 0];
    unsigned c1 = h[lane * 4 + 1];
    unsigned c2 = h[lane * 4 + 2];
    unsigned c3 = h[lane * 4 + 3];
    unsigned S = c0 + c1 + c2 + c3;
    unsigned T = S;
    #pragma unroll
    for (int off = 1; off < 64; off <<= 1) {
        unsigned t = __shfl_down(T, off, 64);
        T += (lane + off < 64) ? t : 0u;
    }
    unsigned Tn = T - S;
    unsigned sfx3 = c3 + Tn, sfx2 = c2 + sfx3, sfx1 = c1 + sfx2, sfx0 = c0 + sfx1;
    int hit = -1; unsigned nk = 0u;
    if (sfx3 >= kr && Tn   < kr) { hit = lane * 4 + 3; nk = kr - Tn; }
    if (sfx2 >= kr && sfx3 < kr) { hit = lane * 4 + 2; nk = kr - sfx3; }
    if (sfx1 >= kr && sfx2 < kr) { hit = lane * 4 + 1; nk = kr - sfx2; }
    if (sfx0 >= kr && sfx1 < kr) { hit = lane * 4 + 0; nk = kr - sfx1; }
    unsigned long long mask = __ballot(hit >= 0);
    int src = __ffsll((unsigned long long)mask) - 1;
    int bin = __shfl(hit, src, 64);
    kr = (unsigned)__shfl((int)nk, src, 64);
    return bin;
}

// ---------------- Kernel 2: MFMA scores + top-k + softmax + MFMA PV ----------------
__global__ __launch_bounds__(256, 3) void k_attn(
    const float* __restrict__ Xn, const float* __restrict__ Qb,
    const short* __restrict__ Kbf, const short* __restrict__ XbfT,
    const float* __restrict__ stg, const int* __restrict__ topk_p,
    float* __restrict__ Z)
{
    __shared__ __align__(16) unsigned short sbuf[RR * LLP];   // 29952 B: s as u16, then e as bf16
    __shared__ unsigned h1[RR * 256];
    __shared__ unsigned h2[RR * 256];
    __shared__ int b0_lds[RR];
    __shared__ int thr_lds[RR];
    __shared__ int gmax_lds[RR];
    __shared__ int gmax_w[4][RR];
    __shared__ float redsum[4][RR];
    __shared__ float red_pv[4][RR][64];

    int tid = threadIdx.x;
    int lane = tid & 63, wv = tid >> 6;
    int hi = lane >> 5, l31 = lane & 31;
    int b = blockIdx.x & 7;
    int chunk = blockIdx.x >> 3;
    int row0 = chunk * RR;
    char* sb = (char*)sbuf;

    for (int i = tid; i < RR * 256; i += 256) { h1[i] = 0u; h2[i] = 0u; }

    int keff;
    { int tk = *topk_p; keff = (tk < 5) ? tk * NN : tk; }

    // ---- Q A-fragments (rows = lane&31, only rows<6 real) ----
    bf16x8 qf[4];
    bf16x8 zero8 = {0, 0, 0, 0, 0, 0, 0, 0};
    int arow = l31;
    #pragma unroll
    for (int kk = 0; kk < 4; kk++) {
        if (arow < RR) {
            const float* qp = Qb + ((size_t)b * LL + row0 + arow) * 64 + kk * 16 + hi * 8;
            bf16x8 f;
            #pragma unroll
            for (int e = 0; e < 8; e++) f[e] = f2bf(qp[e]);
            qf[kk] = f;
        } else qf[kk] = zero8;
    }
    __syncthreads();   // hist zero visible before B-phase atomics

    // ---- scores via MFMA + fused sigmoid*stg + u16 store + hist + row max ----
    const float* stgp = stg + ((size_t)b * LL + row0) * LL;
    int t0 = wv * 20;
    int t1 = (t0 + 20 < 78) ? t0 + 20 : 78;
    int gmx[4] = {0, 0, 0, 0};
    for (int t = t0; t < t1; ++t) {
        int j0 = t * 32;
        f32x16 c = {0.f,0.f,0.f,0.f,0.f,0.f,0.f,0.f,0.f,0.f,0.f,0.f,0.f,0.f,0.f,0.f};
        const short* kbase = Kbf + ((size_t)b * LLP + j0 + l31) * 64 + hi * 8;
        #pragma unroll
        for (int kk = 0; kk < 4; kk++) {
            bf16x8 kv = *(const bf16x8*)(kbase + kk * 16);
            c = __builtin_amdgcn_mfma_f32_32x32x16_bf16(qf[kk], kv, c, 0, 0, 0);
        }
        int j = j0 + l31;
        bool jv = (j < LL);
        #pragma unroll
        for (int reg = 0; reg < 4; reg++) {
            int r = reg + 4 * hi;
            if (r < RR) {
                float sg = 1.0f / (1.0f + __expf(c[reg] * -0.125f));
                float sv = jv ? sg * stgp[(size_t)r * LL + j] : 0.f;
                int g = (int)(sv * 65536.0f); g = (g > 65535) ? 65535 : g;
                *(unsigned short*)(sb + sw_off(r, r * ROWB + j * 2)) = (unsigned short)g;
                if (jv) {
                    atomicAdd(&h1[r * 256 + (g >> 8)], 1u);
                    gmx[reg] = (g > gmx[reg]) ? g : gmx[reg];
                }
            }
        }
    }
    #pragma unroll
    for (int reg = 0; reg < 4; reg++) {
        #pragma unroll
        for (int off = 1; off < 32; off <<= 1) {
            int o2 = __shfl_xor(gmx[reg], off, 64);
            gmx[reg] = (o2 > gmx[reg]) ? o2 : gmx[reg];
        }
    }
    if (l31 == 0) {
        #pragma unroll
        for (int reg = 0; reg < 4; reg++) {
            int r = reg + 4 * hi;
            if (r < RR) gmax_w[wv][r] = gmx[reg];
        }
    }
    __syncthreads();   // sbuf + h1 + gmax_w complete

    if (tid < RR) {
        int m0 = gmax_w[0][tid] > gmax_w[1][tid] ? gmax_w[0][tid] : gmax_w[1][tid];
        int m1 = gmax_w[2][tid] > gmax_w[3][tid] ? gmax_w[2][tid] : gmax_w[3][tid];
        gmax_lds[tid] = m0 > m1 ? m0 : m1;
    }

    // ---- pass-0 scan ----
    unsigned krA = (unsigned)keff, krB = (unsigned)keff;
    {
        int binA = scan_select(&h1[wv * 256], lane, krA);
        if (lane == 0) b0_lds[wv] = binA;
        if (wv < 2) {
            int binB = scan_select(&h1[(wv + 4) * 256], lane, krB);
            if (lane == 0) b0_lds[wv + 4] = binB;
        }
    }
    __syncthreads();

    // ---- refine pass ----
    {
        int b0c[RR];
        #pragma unroll
        for (int r = 0; r < RR; r++) b0c[r] = b0_lds[r];
        #pragma unroll
        for (int sl = 0; sl < 10; sl++) {
            int j = tid + sl * 256;
            if (j < LL) {
                #pragma unroll
                for (int r = 0; r < RR; r++) {
                    int g = *(const unsigned short*)(sb + sw_off(r, r * ROWB + j * 2));
                    if ((g >> 8) == b0c[r]) atomicAdd(&h2[r * 256 + (g & 255)], 1u);
                }
            }
        }
    }
    __syncthreads();
    {
        int binA = scan_select(&h2[wv * 256], lane, krA);
        if (lane == 0) thr_lds[wv] = b0_lds[wv] * 256 + binA;
        if (wv < 2) {
            int binB = scan_select(&h2[(wv + 4) * 256], lane, krB);
            if (lane == 0) thr_lds[wv + 4] = b0_lds[wv + 4] * 256 + binB;
        }
    }
    __syncthreads();

    // ---- E: e = (g>thr || g==gmax) ? exp((g-gmax)/65536) : 0 ; overwrite LDS with bf16 ----
    int gthr[RR], gmaxv[RR];
    float smr[RR];
    #pragma unroll
    for (int r = 0; r < RR; r++) { gthr[r] = thr_lds[r]; gmaxv[r] = gmax_lds[r]; smr[r] = 0.f; }
    #pragma unroll
    for (int sl = 0; sl < 10; sl++) {
        int j = tid + sl * 256;
        if (j < LL) {
            #pragma unroll
            for (int r = 0; r < RR; r++) {
                unsigned short* p = (unsigned short*)(sb + sw_off(r, r * ROWB + j * 2));
                int g = *p;
                float e = (g > gthr[r] || g == gmaxv[r])
                        ? __expf((float)(g - gmaxv[r]) * (1.0f / 65536.0f)) : 0.f;
                *p = (unsigned short)f2bf(e);
                smr[r] += e;
            }
        }
    }
    #pragma unroll
    for (int r = 0; r < RR; r++) {
        float v = smr[r];
        #pragma unroll
        for (int o = 32; o; o >>= 1) v += __shfl_xor(v, o, 64);
        smr[r] = v;
    }
    if (lane == 0) {
        #pragma unroll
        for (int r = 0; r < RR; r++) redsum[wv][r] = smr[r];
    }
    __syncthreads();   // e in LDS complete

    // ---- PV via MFMA: O = e(6x2496) @ X(2496x64), k split across waves ----
    f32x16 p0 = {0.f,0.f,0.f,0.f,0.f,0.f,0.f,0.f,0.f,0.f,0.f,0.f,0.f,0.f,0.f,0.f};
    f32x16 p1 = p0;
    {
        bool av = (arow < RR);
        const short* xb0 = XbfT + ((size_t)b * 64 + l31) * LLP + hi * 8;
        const short* xb1 = XbfT + ((size_t)b * 64 + 32 + l31) * LLP + hi * 8;
        int kk0 = wv * 39;
        for (int kk = kk0; kk < kk0 + 39; ++kk) {
            bf16x8 ea = zero8;
            if (av) ea = *(const bf16x8*)(sb + sw_off(arow, arow * ROWB + kk * 32 + hi * 16));
            bf16x8 x0 = *(const bf16x8*)(xb0 + kk * 16);
            bf16x8 x1 = *(const bf16x8*)(xb1 + kk * 16);
            p0 = __builtin_amdgcn_mfma_f32_32x32x16_bf16(ea, x0, p0, 0, 0, 0);
            p1 = __builtin_amdgcn_mfma_f32_32x32x16_bf16(ea, x1, p1, 0, 0, 0);
        }
    }
    #pragma unroll
    for (int reg = 0; reg < 4; reg++) {
        int r = reg + 4 * hi;
        if (r < RR) {
            red_pv[wv][r][l31]      = p0[reg];
            red_pv[wv][r][32 + l31] = p1[reg];
        }
    }
    __syncthreads();

    for (int i = tid; i < RR * 64; i += 256) {
        int r = i >> 6, d = i & 63;
        float rcp = 1.0f / (redsum[0][r] + redsum[1][r] + redsum[2][r] + redsum[3][r]);
        float o = (red_pv[0][r][d] + red_pv[1][r][d]) + (red_pv[2][r][d] + red_pv[3][r][d]);
        size_t grow = (size_t)b * LL + row0 + r;
        Z[grow * 64 + d] = o * rcp + Xn[grow * 64 + d];
    }
}

// ---------------- Kernel 3: fused LN + FFN + residual ----------------
__global__ __launch_bounds__(256) void k_ffn(
    const float* __restrict__ Zb, const float* __restrict__ fg, const float* __restrict__ fb,
    const float* __restrict__ w1, const float* __restrict__ b1,
    const float* __restrict__ w2, const float* __restrict__ b2,
    float* __restrict__ out)
{
    const int G = 16;
    __shared__ float zr[G][64];
    __shared__ float zl[G][64];
    __shared__ float h[G][DHID];
    int tid = threadIdx.x;
    int w = tid >> 6, lane = tid & 63;
    size_t row0 = (size_t)blockIdx.x * G;
    for (int rr = w; rr < G; rr += 4) {
        float zv = Zb[(row0 + rr) * 64 + lane];
        zr[rr][lane] = zv;
        float m = zv;
        #pragma unroll
        for (int o = 32; o; o >>= 1) m += __shfl_xor(m, o, 64);
        m *= (1.0f / 64.0f);
        float dv = zv - m;
        float var = dv * dv;
        #pragma unroll
        for (int o = 32; o; o >>= 1) var += __shfl_xor(var, o, 64);
        var *= (1.0f / 64.0f);
        zl[rr][lane] = dv * (1.0f / sqrtf(var + LNEPS)) * fg[lane] + fb[lane];
    }
    __syncthreads();
    float hacc[G];
    #pragma unroll
    for (int g = 0; g < G; g++) hacc[g] = 0.f;
    for (int d = 0; d < 64; d++) {
        float wv1 = w1[d * DHID + tid];
        #pragma unroll
        for (int g = 0; g < G; g++) hacc[g] += zl[g][d] * wv1;
    }
    float b1v = b1[tid];
    #pragma unroll
    for (int g = 0; g < G; g++) h[g][tid] = fmaxf(hacc[g] + b1v, 0.f);
    __syncthreads();
    float oacc[4] = {0.f, 0.f, 0.f, 0.f};
    for (int i = 0; i < DHID; i++) {
        float wv2 = w2[i * 64 + lane];
        #pragma unroll
        for (int rr = 0; rr < 4; rr++) oacc[rr] += h[w * 4 + rr][i] * wv2;
    }
    float b2v = b2[lane];
    #pragma unroll
    for (int rr = 0; rr < 4; rr++)
        out[(row0 + w * 4 + rr) * 64 + lane] = zr[w * 4 + rr][lane] + oacc[rr] + b2v;
}

extern "C" void kernel_launch(void* const* d_in, const int* in_sizes, int n_in,
                              void* d_out, int out_size, void* d_ws, size_t ws_size,
                              hipStream_t stream)
{
    const float* x      = (const float*)d_in[0];
    const float* stg    = (const float*)d_in[1];
    const float* Wq     = (const float*)d_in[2];
    const float* bq     = (const float*)d_in[3];
    const float* Wk     = (const float*)d_in[4];
    const float* bk     = (const float*)d_in[5];
    const float* gamma  = (const float*)d_in[6];
    const float* beta   = (const float*)d_in[7];
    const float* fgamma = (const float*)d_in[8];
    const float* fbeta  = (const float*)d_in[9];
    const float* w1     = (const float*)d_in[10];
    const float* b1     = (const float*)d_in[11];
    const float* w2     = (const float*)d_in[12];
    const float* b2     = (const float*)d_in[13];
    const int*   topk   = (const int*)d_in[14];
    float* out = (float*)d_out;

    const size_t rows = (size_t)NBATCH * NTOK * NN;   // 19872
    float* Xn = (float*)d_ws;
    float* Qb = Xn + rows * 64;
    float* Z  = Qb + rows * 64;
    short* Kbf  = (short*)(Z + rows * 64);
    short* XbfT = Kbf + (size_t)NBATCH * LLP * 64;

    k_lnproj<<<(int)(rows / 4), 256, 0, stream>>>(x, Wq, bq, Wk, bk, gamma, beta, Xn, Qb, Kbf);
    k_prep<<<NBATCH * 39, 256, 0, stream>>>(Xn, XbfT, Kbf);
    k_attn<<<NBATCH * (LL / RR), 256, 0, stream>>>(Xn, Qb, Kbf, XbfT, stg, topk, Z);
    k_ffn<<<(int)(rows / 16), 256, 0, stream>>>(Z, fgamma, fbeta, w1, b1, w2, b2, out);
}

// Round 5
// 388.044 us; speedup vs baseline: 2.0229x; 1.2106x over previous
//
#include <hip/hip_runtime.h>

#define NBATCH 8
#define NTOK   12
#define NN     207
#define DHID   256
#define LL     2484      // NTOK*NN
#define LLP    2496      // padded to multiple of 32
#define RR     6         // rows per block in k_attn
#define ROWB   (LLP*2)   // bytes per row of s/e LDS buffer
#define LNEPS  1e-5f

typedef __attribute__((ext_vector_type(8)))  short bf16x8;
typedef __attribute__((ext_vector_type(16))) float f32x16;

__device__ __forceinline__ short f2bf(float f) {
    unsigned u = __float_as_uint(f);
    unsigned r = (u + 0x7FFFu + ((u >> 16) & 1u)) >> 16;
    return (short)r;
}
__device__ __forceinline__ unsigned sw_off(int r, unsigned byte) {
    return byte ^ ((unsigned)(r & 7) << 4);
}

// ---------------- Kernel 1: LayerNorm + Q/K projections ----------------
__global__ __launch_bounds__(256) void k_lnproj(
    const float* __restrict__ x, const float* __restrict__ Wq, const float* __restrict__ bq,
    const float* __restrict__ Wk, const float* __restrict__ bk,
    const float* __restrict__ gamma, const float* __restrict__ beta,
    float* __restrict__ Xn, float* __restrict__ Qb, short* __restrict__ Kbf)
{
    __shared__ float xrow[4][64];
    int w = threadIdx.x >> 6, lane = threadIdx.x & 63;
    size_t row = (size_t)blockIdx.x * 4 + w;
    float xv = x[row * 64 + lane];
    float m = xv;
    #pragma unroll
    for (int o = 32; o; o >>= 1) m += __shfl_xor(m, o, 64);
    m *= (1.0f / 64.0f);
    float dv = xv - m;
    float var = dv * dv;
    #pragma unroll
    for (int o = 32; o; o >>= 1) var += __shfl_xor(var, o, 64);
    var *= (1.0f / 64.0f);
    float xg = dv * (1.0f / sqrtf(var + LNEPS)) * gamma[lane] + beta[lane];
    Xn[row * 64 + lane] = xg;
    xrow[w][lane] = xg;
    __syncthreads();
    float q = bq[lane], k = bk[lane];
    #pragma unroll 8
    for (int e = 0; e < 64; e++) {
        float xe = xrow[w][e];
        q += xe * Wq[e * 64 + lane];
        k += xe * Wk[e * 64 + lane];
    }
    Qb[row * 64 + lane] = q;
    int br = (int)(row / LL);
    int jl = (int)(row - (size_t)br * LL);
    Kbf[((size_t)br * LLP + jl) * 64 + lane] = f2bf(k);
}

// ---------------- Kernel 1b: transpose Xn -> bf16 X^T, zero pads ----------------
__global__ __launch_bounds__(256) void k_prep(
    const float* __restrict__ Xn, short* __restrict__ XbfT, short* __restrict__ Kbf)
{
    __shared__ float tile[64][65];
    int bb = blockIdx.x & 7;
    int jt = blockIdx.x >> 3;          // 0..38
    int j0 = jt * 64;
    for (int i = threadIdx.x; i < 4096; i += 256) {
        int jl = i >> 6, d = i & 63;
        int j = j0 + jl;
        tile[jl][d] = (j < LL) ? Xn[((size_t)bb * LL + j) * 64 + d] : 0.f;
    }
    __syncthreads();
    for (int i = threadIdx.x; i < 4096; i += 256) {
        int d = i >> 6, jl = i & 63;
        XbfT[((size_t)bb * 64 + d) * LLP + j0 + jl] = f2bf(tile[jl][d]);
    }
    if (jt == 38) {
        for (int i = threadIdx.x; i < (LLP - LL) * 64; i += 256) {
            int jl = i >> 6, d = i & 63;
            Kbf[((size_t)bb * LLP + LL + jl) * 64 + d] = 0;
        }
    }
}

// --------------- suffix-scan select ---------------
__device__ __forceinline__ int scan_select(const unsigned* __restrict__ h, int lane, unsigned& kr)
{
    unsigned c0 = h[lane * 4 + 0];
    unsigned c1 = h[lane * 4 + 1];
    unsigned c2 = h[lane * 4 + 2];
    unsigned c3 = h[lane * 4 + 3];
    unsigned S = c0 + c1 + c2 + c3;
    unsigned T = S;
    #pragma unroll
    for (int off = 1; off < 64; off <<= 1) {
        unsigned t = __shfl_down(T, off, 64);
        T += (lane + off < 64) ? t : 0u;
    }
    unsigned Tn = T - S;
    unsigned sfx3 = c3 + Tn, sfx2 = c2 + sfx3, sfx1 = c1 + sfx2, sfx0 = c0 + sfx1;
    int hit = -1; unsigned nk = 0u;
    if (sfx3 >= kr && Tn   < kr) { hit = lane * 4 + 3; nk = kr - Tn; }
    if (sfx2 >= kr && sfx3 < kr) { hit = lane * 4 + 2; nk = kr - sfx3; }
    if (sfx1 >= kr && sfx2 < kr) { hit = lane * 4 + 1; nk = kr - sfx2; }
    if (sfx0 >= kr && sfx1 < kr) { hit = lane * 4 + 0; nk = kr - sfx1; }
    unsigned long long mask = __ballot(hit >= 0);
    int src = __ffsll((unsigned long long)mask) - 1;
    int bin = __shfl(hit, src, 64);
    kr = (unsigned)__shfl((int)nk, src, 64);
    return bin;
}

// ---------------- Kernel 2: MFMA scores + top-k + softmax + MFMA PV ----------------
__global__ __launch_bounds__(256, 4) void k_attn(
    const float* __restrict__ Xn, const float* __restrict__ Qb,
    const short* __restrict__ Kbf, const short* __restrict__ XbfT,
    const float* __restrict__ stg, const int* __restrict__ topk_p,
    float* __restrict__ Z)
{
    __shared__ __align__(16) unsigned short sbuf[RR * LLP];   // 29952 B: s as u16, then e as bf16
    __shared__ __align__(16) unsigned hist[RR * 256];         // 6144 B; re-used as red_pv
    __shared__ int b0_lds[RR];
    __shared__ int thr_lds[RR];
    __shared__ int gmax_lds[RR];
    __shared__ int gmax_w[4][RR];
    __shared__ float redsum[4][RR];

    float (*red_pv)[RR][64] = (float (*)[RR][64])hist;        // union: hist dead before PV

    int tid = threadIdx.x;
    int lane = tid & 63, wv = tid >> 6;
    int hi = lane >> 5, l31 = lane & 31;
    int b = blockIdx.x & 7;
    int chunk = blockIdx.x >> 3;
    int row0 = chunk * RR;
    char* sb = (char*)sbuf;

    for (int i = tid; i < RR * 256; i += 256) hist[i] = 0u;

    int keff;
    { int tk = *topk_p; keff = (tk < 5) ? tk * NN : tk; }

    // ---- Q A-fragments (rows = lane&31, only rows<6 real) ----
    bf16x8 qf[4];
    bf16x8 zero8 = {0, 0, 0, 0, 0, 0, 0, 0};
    int arow = l31;
    #pragma unroll
    for (int kk = 0; kk < 4; kk++) {
        if (arow < RR) {
            const float* qp = Qb + ((size_t)b * LL + row0 + arow) * 64 + kk * 16 + hi * 8;
            bf16x8 f;
            #pragma unroll
            for (int e = 0; e < 8; e++) f[e] = f2bf(qp[e]);
            qf[kk] = f;
        } else qf[kk] = zero8;
    }

    // ---- B1: MFMA scores -> sigmoid -> u16 to LDS (no global loads in chain) ----
    int t0 = wv * 20;
    int t1 = (t0 + 20 < 78) ? t0 + 20 : 78;
    for (int t = t0; t < t1; ++t) {
        int j0 = t * 32;
        f32x16 c = {0.f,0.f,0.f,0.f,0.f,0.f,0.f,0.f,0.f,0.f,0.f,0.f,0.f,0.f,0.f,0.f};
        const short* kbase = Kbf + ((size_t)b * LLP + j0 + l31) * 64 + hi * 8;
        #pragma unroll
        for (int kk = 0; kk < 4; kk++) {
            bf16x8 kv = *(const bf16x8*)(kbase + kk * 16);
            c = __builtin_amdgcn_mfma_f32_32x32x16_bf16(qf[kk], kv, c, 0, 0, 0);
        }
        int j = j0 + l31;
        bool jv = (j < LL);
        #pragma unroll
        for (int reg = 0; reg < 4; reg++) {
            int r = reg + 4 * hi;
            if (r < RR) {
                float sg = 1.0f / (1.0f + __expf(c[reg] * -0.125f));
                int us = (int)(sg * 65536.0f); us = (us > 65535) ? 65535 : us;
                if (!jv) us = 0;
                *(unsigned short*)(sb + sw_off(r, r * ROWB + j * 2)) = (unsigned short)us;
            }
        }
    }
    __syncthreads();   // sbuf(us) + hist zero visible

    // ---- B2: coalesced stg multiply + histogram + gmax (tid-strided) ----
    const float* stgp = stg + ((size_t)b * LL + row0) * LL;
    int gmx[RR];
    #pragma unroll
    for (int r = 0; r < RR; r++) gmx[r] = 0;
    #pragma unroll 1
    for (int sl = 0; sl < 10; sl++) {
        int j = tid + sl * 256;
        if (j < LL) {
            float stgv[RR];
            #pragma unroll
            for (int r = 0; r < RR; r++) stgv[r] = stgp[(size_t)r * LL + j];
            #pragma unroll
            for (int r = 0; r < RR; r++) {
                unsigned short* p = (unsigned short*)(sb + sw_off(r, r * ROWB + j * 2));
                int us = *p;
                int g = (int)((float)us * stgv[r]);
                *p = (unsigned short)g;
                atomicAdd(&hist[r * 256 + (g >> 8)], 1u);
                gmx[r] = (g > gmx[r]) ? g : gmx[r];
            }
        }
    }
    #pragma unroll
    for (int r = 0; r < RR; r++) {
        #pragma unroll
        for (int off = 1; off < 64; off <<= 1) {
            int o2 = __shfl_xor(gmx[r], off, 64);
            gmx[r] = (o2 > gmx[r]) ? o2 : gmx[r];
        }
    }
    if (lane == 0) {
        #pragma unroll
        for (int r = 0; r < RR; r++) gmax_w[wv][r] = gmx[r];
    }
    __syncthreads();   // hist + gmax_w + sbuf(g) complete

    if (tid < RR) {
        int m0 = gmax_w[0][tid] > gmax_w[1][tid] ? gmax_w[0][tid] : gmax_w[1][tid];
        int m1 = gmax_w[2][tid] > gmax_w[3][tid] ? gmax_w[2][tid] : gmax_w[3][tid];
        gmax_lds[tid] = m0 > m1 ? m0 : m1;
    }

    // ---- pass-0 scan ----
    unsigned krA = (unsigned)keff, krB = (unsigned)keff;
    {
        int binA = scan_select(&hist[wv * 256], lane, krA);
        if (lane == 0) b0_lds[wv] = binA;
        if (wv < 2) {
            int binB = scan_select(&hist[(wv + 4) * 256], lane, krB);
            if (lane == 0) b0_lds[wv + 4] = binB;
        }
    }
    __syncthreads();   // scans done reading hist
    for (int i = tid; i < RR * 256; i += 256) hist[i] = 0u;
    __syncthreads();   // re-zero visible

    // ---- refine pass ----
    {
        int b0c[RR];
        #pragma unroll
        for (int r = 0; r < RR; r++) b0c[r] = b0_lds[r];
        #pragma unroll 1
        for (int sl = 0; sl < 10; sl++) {
            int j = tid + sl * 256;
            if (j < LL) {
                #pragma unroll
                for (int r = 0; r < RR; r++) {
                    int g = *(const unsigned short*)(sb + sw_off(r, r * ROWB + j * 2));
                    if ((g >> 8) == b0c[r]) atomicAdd(&hist[r * 256 + (g & 255)], 1u);
                }
            }
        }
    }
    __syncthreads();
    {
        int binA = scan_select(&hist[wv * 256], lane, krA);
        if (lane == 0) thr_lds[wv] = b0_lds[wv] * 256 + binA;
        if (wv < 2) {
            int binB = scan_select(&hist[(wv + 4) * 256], lane, krB);
            if (lane == 0) thr_lds[wv + 4] = b0_lds[wv + 4] * 256 + binB;
        }
    }
    __syncthreads();

    // ---- E: e = (g>thr || g==gmax) ? exp((g-gmax)/65536) : 0 ; overwrite LDS with bf16 ----
    int gthr[RR], gmaxv[RR];
    float smr[RR];
    #pragma unroll
    for (int r = 0; r < RR; r++) { gthr[r] = thr_lds[r]; gmaxv[r] = gmax_lds[r]; smr[r] = 0.f; }
    #pragma unroll 1
    for (int sl = 0; sl < 10; sl++) {
        int j = tid + sl * 256;
        if (j < LL) {
            #pragma unroll
            for (int r = 0; r < RR; r++) {
                unsigned short* p = (unsigned short*)(sb + sw_off(r, r * ROWB + j * 2));
                int g = *p;
                float e = (g > gthr[r] || g == gmaxv[r])
                        ? __expf((float)(g - gmaxv[r]) * (1.0f / 65536.0f)) : 0.f;
                *p = (unsigned short)f2bf(e);
                smr[r] += e;
            }
        }
    }
    #pragma unroll
    for (int r = 0; r < RR; r++) {
        float v = smr[r];
        #pragma unroll
        for (int o = 32; o; o >>= 1) v += __shfl_xor(v, o, 64);
        smr[r] = v;
    }
    if (lane == 0) {
        #pragma unroll
        for (int r = 0; r < RR; r++) redsum[wv][r] = smr[r];
    }
    __syncthreads();   // e in LDS complete; hist no longer needed -> red_pv

    // ---- PV via MFMA: O = e(6x2496) @ X(2496x64), k split across waves ----
    f32x16 p0 = {0.f,0.f,0.f,0.f,0.f,0.f,0.f,0.f,0.f,0.f,0.f,0.f,0.f,0.f,0.f,0.f};
    f32x16 p1 = p0;
    {
        bool av = (arow < RR);
        const short* xb0 = XbfT + ((size_t)b * 64 + l31) * LLP + hi * 8;
        const short* xb1 = XbfT + ((size_t)b * 64 + 32 + l31) * LLP + hi * 8;
        int kk0 = wv * 39;
        for (int kk = kk0; kk < kk0 + 39; ++kk) {
            bf16x8 ea = zero8;
            if (av) ea = *(const bf16x8*)(sb + sw_off(arow, arow * ROWB + kk * 32 + hi * 16));
            bf16x8 x0 = *(const bf16x8*)(xb0 + kk * 16);
            bf16x8 x1 = *(const bf16x8*)(xb1 + kk * 16);
            p0 = __builtin_amdgcn_mfma_f32_32x32x16_bf16(ea, x0, p0, 0, 0, 0);
            p1 = __builtin_amdgcn_mfma_f32_32x32x16_bf16(ea, x1, p1, 0, 0, 0);
        }
    }
    #pragma unroll
    for (int reg = 0; reg < 4; reg++) {
        int r = reg + 4 * hi;
        if (r < RR) {
            red_pv[wv][r][l31]      = p0[reg];
            red_pv[wv][r][32 + l31] = p1[reg];
        }
    }
    __syncthreads();

    for (int i = tid; i < RR * 64; i += 256) {
        int r = i >> 6, d = i & 63;
        float rcp = 1.0f / (redsum[0][r] + redsum[1][r] + redsum[2][r] + redsum[3][r]);
        float o = (red_pv[0][r][d] + red_pv[1][r][d]) + (red_pv[2][r][d] + red_pv[3][r][d]);
        size_t grow = (size_t)b * LL + row0 + r;
        Z[grow * 64 + d] = o * rcp + Xn[grow * 64 + d];
    }
}

// ---------------- Kernel 3: fused LN + FFN + residual ----------------
__global__ __launch_bounds__(256) void k_ffn(
    const float* __restrict__ Zb, const float* __restrict__ fg, const float* __restrict__ fb,
    const float* __restrict__ w1, const float* __restrict__ b1,
    const float* __restrict__ w2, const float* __restrict__ b2,
    float* __restrict__ out)
{
    const int G = 16;
    __shared__ float zr[G][64];
    __shared__ float zl[G][64];
    __shared__ float h[G][DHID];
    int tid = threadIdx.x;
    int w = tid >> 6, lane = tid & 63;
    size_t row0 = (size_t)blockIdx.x * G;
    for (int rr = w; rr < G; rr += 4) {
        float zv = Zb[(row0 + rr) * 64 + lane];
        zr[rr][lane] = zv;
        float m = zv;
        #pragma unroll
        for (int o = 32; o; o >>= 1) m += __shfl_xor(m, o, 64);
        m *= (1.0f / 64.0f);
        float dv = zv - m;
        float var = dv * dv;
        #pragma unroll
        for (int o = 32; o; o >>= 1) var += __shfl_xor(var, o, 64);
        var *= (1.0f / 64.0f);
        zl[rr][lane] = dv * (1.0f / sqrtf(var + LNEPS)) * fg[lane] + fb[lane];
    }
    __syncthreads();
    float hacc[G];
    #pragma unroll
    for (int g = 0; g < G; g++) hacc[g] = 0.f;
    for (int d = 0; d < 64; d++) {
        float wv1 = w1[d * DHID + tid];
        #pragma unroll
        for (int g = 0; g < G; g++) hacc[g] += zl[g][d] * wv1;
    }
    float b1v = b1[tid];
    #pragma unroll
    for (int g = 0; g < G; g++) h[g][tid] = fmaxf(hacc[g] + b1v, 0.f);
    __syncthreads();
    float oacc[4] = {0.f, 0.f, 0.f, 0.f};
    for (int i = 0; i < DHID; i++) {
        float wv2 = w2[i * 64 + lane];
        #pragma unroll
        for (int rr = 0; rr < 4; rr++) oacc[rr] += h[w * 4 + rr][i] * wv2;
    }
    float b2v = b2[lane];
    #pragma unroll
    for (int rr = 0; rr < 4; rr++)
        out[(row0 + w * 4 + rr) * 64 + lane] = zr[w * 4 + rr][lane] + oacc[rr] + b2v;
}

extern "C" void kernel_launch(void* const* d_in, const int* in_sizes, int n_in,
                              void* d_out, int out_size, void* d_ws, size_t ws_size,
                              hipStream_t stream)
{
    const float* x      = (const float*)d_in[0];
    const float* stg    = (const float*)d_in[1];
    const float* Wq     = (const float*)d_in[2];
    const float* bq     = (const float*)d_in[3];
    const float* Wk     = (const float*)d_in[4];
    const float* bk     = (const float*)d_in[5];
    const float* gamma  = (const float*)d_in[6];
    const float* beta   = (const float*)d_in[7];
    const float* fgamma = (const float*)d_in[8];
    const float* fbeta  = (const float*)d_in[9];
    const float* w1     = (const float*)d_in[10];
    const float* b1     = (const float*)d_in[11];
    const float* w2     = (const float*)d_in[12];
    const float* b2     = (const float*)d_in[13];
    const int*   topk   = (const int*)d_in[14];
    float* out = (float*)d_out;

    const size_t rows = (size_t)NBATCH * NTOK * NN;   // 19872
    float* Xn = (float*)d_ws;
    float* Qb = Xn + rows * 64;
    float* Z  = Qb + rows * 64;
    short* Kbf  = (short*)(Z + rows * 64);
    short* XbfT = Kbf + (size_t)NBATCH * LLP * 64;

    k_lnproj<<<(int)(rows / 4), 256, 0, stream>>>(x, Wq, bq, Wk, bk, gamma, beta, Xn, Qb, Kbf);
    k_prep<<<NBATCH * 39, 256, 0, stream>>>(Xn, XbfT, Kbf);
    k_attn<<<NBATCH * (LL / RR), 256, 0, stream>>>(Xn, Qb, Kbf, XbfT, stg, topk, Z);
    k_ffn<<<(int)(rows / 16), 256, 0, stream>>>(Z, fgamma, fbeta, w1, b1, w2, b2, out);
}